// Round 11
// baseline (231.265 us; speedup 1.0000x reference)
//
#include <hip/hip_runtime.h>
#include <hip/hip_bf16.h>
#include <stdint.h>

// Problem constants (B=4, L=4096, D=1024, K=3)
#define B_SZ   4
#define L_SEQ  4096
#define D_DIM  1024
#define M_TOT  (B_SZ * L_SEQ)   // 16384

typedef __bf16 bf16;
typedef __attribute__((ext_vector_type(8))) __bf16 bf16x8;
typedef __attribute__((ext_vector_type(4))) float   f32x4;

#define GLOAD_LDS16(g, l)                                                     \
  __builtin_amdgcn_global_load_lds(                                           \
      (const __attribute__((address_space(1))) void*)(g),                     \
      (__attribute__((address_space(3))) void*)(l), 16, 0, 0)

// ---------------------------------------------------------------------------
// Kernel 1: w_pw fp32 -> bf16 (2MB result stays XCD-L2-resident for the GEMM).
// ---------------------------------------------------------------------------
__global__ __launch_bounds__(256) void cvt_kernel(
    const float* __restrict__ w_pw, bf16* __restrict__ wpwb) {
  int i = (blockIdx.x * 256 + threadIdx.x) * 8;
  float4 a = *(const float4*)(w_pw + i);
  float4 b = *(const float4*)(w_pw + i + 4);
  union { bf16 h[8]; int4 v; } r;
  r.h[0] = (bf16)a.x; r.h[1] = (bf16)a.y; r.h[2] = (bf16)a.z; r.h[3] = (bf16)a.w;
  r.h[4] = (bf16)b.x; r.h[5] = (bf16)b.y; r.h[6] = (bf16)b.z; r.h[7] = (bf16)b.w;
  *(int4*)(wpwb + i) = r.v;
}

// ---------------------------------------------------------------------------
// Kernel 2: FUSED depthwise-conv + GEMM. 256x128 tile, 512 thr / 8 waves
// (wave tile 64x64, acc[4][4]; 2 waves/SIMD -> 256-reg budget for conv regs).
//   out[m][n] = sum_k conv(x)[m][k] * wpwb[n][k] + b_pw[n]
// 32 K-slices of 32. No y buffer, no dw kernel (-27us, -64MB HBM traffic).
//
// A-staging = conv-in-registers: per thread 2 granules (rows rt, rt+128;
// channel octet c*8 + s*32). Loads 3 x-rows x 32B (+ w_dw 96B + b_dw 32B,
// L1-hot) one FULL SLICE ahead (~2500cy >> HBM latency; this is what r1's
// failed fusion lacked), 3 fp32 FMA/elem, cvt, ds_write_b128 DIRECT to the
// proven swizzled address (both-sides swizzle: write swz == read swz).
// A ring-2 16KB slots [0,32K). Causal guard: only granule-0 rows with
// (m0+rt)%4096 < 2 mask halo rows to 0 (granule-1 rows are >= 128).
//
// B-staging (proven path): gload_lds 1/thread into ring-4 8KB slots
// [32K,64K); source pre-swizzled, LDS dest linear.
//
// VM calculus (batch = B-DMA(1) + x(12)+w(6)+b(2)=20):
//  prologue: B(0),B(1),B(2), xwb(0); VM(0); conv(0)->slot0; xwb(1); lgkm; SB.
//  body(s), s<=28: stageB(s+3); frag reads; VM(1) [queue B(s+2),xwb(s+1),
//    B(s+3) -> retires first two exactly]; conv(s+1)->slot (s+1)&1;
//    issue xwb(s+2); lgkm(0); SB; 16 MFMA.
//  s=29: VM(0), conv(30), xwb(31). s=30: VM(0), conv(31). s=31: bare.
// Lifetime proofs: slot-s A ds_writes (conv at body(s-1)) are lgkm-drained
// before SB(s-1), which precedes all waves' body(s) frag reads. A-slot
// overwrite (conv(s+1) at body(s)) is gated by SB(s-1) rendezvous behind
// which all slice-(s-1) reads drained. B slot (s+3)&3 DMA overwrites the
// slot slice s-1 read -- same rendezvous gate. B(s) retired at body(s-2)'s
// VM + two barriers before its body(s) read.
//
// GRID (64,8) m-fastest: XCD = bx%8 -> all 8 n-blocks of an m-panel share
// an XCD; x panel (1MB) fetched ~once from HBM, 8-way L2 reuse.
// ---------------------------------------------------------------------------
#define EP_ROWP 68
#define SB  __builtin_amdgcn_s_barrier()
#define SCB __builtin_amdgcn_sched_barrier(0)
#define VM(N) asm volatile("s_waitcnt vmcnt(" #N ")" ::: "memory")
#define LGKM0 asm volatile("s_waitcnt lgkmcnt(0)" ::: "memory")

__global__ __launch_bounds__(512, 2) void fused_gemm(
    const float* __restrict__ x, const float* __restrict__ w_dw,
    const float* __restrict__ b_dw, const bf16* __restrict__ Bm,
    const float* __restrict__ bias, float* __restrict__ C) {
  __shared__ __align__(16) char smem[65536];
  // A ring-2: [0,16K),[16K,32K).  B ring-4: [32K,64K) in 8KB slots.

  const int t    = threadIdx.x;
  const int m0   = blockIdx.x * 256;  // grid.x = 64 (m) — fastest
  const int n0   = blockIdx.y * 128;  // grid.y = 8 (n)
  const int lane = t & 63;
  const int wv   = t >> 6;    // 0..7
  const int wm4  = wv >> 1;   // 0..3: m-quarter (64 rows of 256)
  const int wn2  = wv & 1;    // 0..1: n-half (64 cols of 128)
  const int lrow = lane & 15;
  const int q    = lane >> 4;

  // frag read bases (proven swizzle): off = row*64 + (q ^ ((row>>1)&3))*16
  const unsigned cxr   = (((unsigned)q ^ (((unsigned)lrow >> 1) & 3)) << 4);
  const unsigned baseA = (unsigned)((wm4 * 64 + lrow) * 64) + cxr;
  const unsigned baseB = (unsigned)((wn2 * 64 + lrow) * 64) + cxr;

  // staging thread geometry
  const int rt = t >> 2;       // 0..127
  const int c  = t & 3;        // k-octet within slice
  const unsigned cS = (unsigned)(c ^ ((rt >> 1) & 3));   // A write chunk swz

  // B DMA (pre-swizzled source, linear LDS dest)
  const bf16* bSrc = Bm + (size_t)(n0 + rt) * D_DIM + (c ^ ((rt >> 1) & 3)) * 8;
  const unsigned wvbase = (unsigned)(wv * 1024);

  // x pointers; causal guard only for granule 0 (granule-1 l >= 128)
  const int mrow0 = m0 + rt;
  const int mrow1 = m0 + 128 + rt;
  const int lloc  = mrow0 & (L_SEQ - 1);
  const bool z2 = (lloc < 2), z1 = (lloc < 1);
  const float* xp0 = x + (size_t)mrow0 * D_DIM + c * 8;
  const float* xp1 = x + (size_t)mrow1 * D_DIM + c * 8;
  const float* xp0m2 = z2 ? xp0 : (xp0 - 2 * D_DIM);   // safe-clamped halo
  const float* xp0m1 = z1 ? xp0 : (xp0 - 1 * D_DIM);

  float xbuf[2][3][8];
  float wbuf[24], bbuf[8];

  auto stageB = [&](int s) {
    GLOAD_LDS16(bSrc + (size_t)s * 32,
                smem + 32768u + (unsigned)((s & 3) * 8192) + wvbase);
  };

  auto issue_xwb = [&](int sl) {   // 12 x-loads + 6 w + 2 b = 20 VMEM
    const int k8 = sl * 32;
    *(float4*)&xbuf[0][0][0] = *(const float4*)(xp0m2 + k8);
    *(float4*)&xbuf[0][0][4] = *(const float4*)(xp0m2 + k8 + 4);
    *(float4*)&xbuf[0][1][0] = *(const float4*)(xp0m1 + k8);
    *(float4*)&xbuf[0][1][4] = *(const float4*)(xp0m1 + k8 + 4);
    *(float4*)&xbuf[0][2][0] = *(const float4*)(xp0 + k8);
    *(float4*)&xbuf[0][2][4] = *(const float4*)(xp0 + k8 + 4);
    *(float4*)&xbuf[1][0][0] = *(const float4*)(xp1 - 2 * D_DIM + k8);
    *(float4*)&xbuf[1][0][4] = *(const float4*)(xp1 - 2 * D_DIM + k8 + 4);
    *(float4*)&xbuf[1][1][0] = *(const float4*)(xp1 - 1 * D_DIM + k8);
    *(float4*)&xbuf[1][1][4] = *(const float4*)(xp1 - 1 * D_DIM + k8 + 4);
    *(float4*)&xbuf[1][2][0] = *(const float4*)(xp1 + k8);
    *(float4*)&xbuf[1][2][4] = *(const float4*)(xp1 + k8 + 4);
    const float* wp = w_dw + (size_t)(k8 + c * 8) * 3;   // 24 floats, 96B-aligned
#pragma unroll
    for (int v = 0; v < 6; ++v)
      *(float4*)&wbuf[v * 4] = *(const float4*)(wp + v * 4);
    *(float4*)&bbuf[0] = *(const float4*)(b_dw + k8 + c * 8);
    *(float4*)&bbuf[4] = *(const float4*)(b_dw + k8 + c * 8 + 4);
  };

  auto conv_store = [&](int sl) {   // conv + cvt + 2x ds_write_b128 (swizzled)
    const unsigned abase = (unsigned)((sl & 1) * 16384);
#pragma unroll
    for (int G = 0; G < 2; ++G) {
      union { bf16 h[8]; int4 v; } o;
#pragma unroll
      for (int c8 = 0; c8 < 8; ++c8) {
        float xm2 = xbuf[G][0][c8], xm1 = xbuf[G][1][c8], xm0 = xbuf[G][2][c8];
        if (G == 0) { xm2 = z2 ? 0.f : xm2; xm1 = z1 ? 0.f : xm1; }
        o.h[c8] = (bf16)fmaf(xm2, wbuf[c8 * 3],
                     fmaf(xm1, wbuf[c8 * 3 + 1],
                       fmaf(xm0, wbuf[c8 * 3 + 2], bbuf[c8])));
      }
      *(int4*)(smem + abase + (unsigned)((G * 128 + rt) * 64) + cS * 16) = o.v;
    }
  };

  f32x4 acc[4][4] = {};

  // mode 0: steady | 1: s=29 | 2: s=30 | 3: s=31
  auto body = [&](int s, int mode) {
    if (mode == 0) stageB(s + 3);
    const char* Ab = (const char*)smem + (size_t)((s & 1) * 16384);
    const char* Bb = (const char*)smem + 32768 + (size_t)((s & 3) * 8192);
    bf16x8 af[4], bf4[4];
#pragma unroll
    for (int j = 0; j < 4; ++j) bf4[j] = *(const bf16x8*)(Bb + baseB + j * 1024);
#pragma unroll
    for (int i = 0; i < 4; ++i) af[i]  = *(const bf16x8*)(Ab + baseA + i * 1024);
    if (mode == 0) { VM(1); } else { VM(0); }
    if (mode <= 2) conv_store(s + 1);
    if (mode <= 1) issue_xwb(s + 2);
    LGKM0;
    SCB;
    SB;
    __builtin_amdgcn_s_setprio(1);
#pragma unroll
    for (int i = 0; i < 4; ++i)
#pragma unroll
      for (int j = 0; j < 4; ++j)
        acc[i][j] = __builtin_amdgcn_mfma_f32_16x16x32_bf16(af[i], bf4[j], acc[i][j], 0, 0, 0);
    __builtin_amdgcn_s_setprio(0);
    SCB;
  };

  // prologue: B(0..2) DMA + xwb(0); full drain (once, cold); conv(0); xwb(1)
  stageB(0); stageB(1); stageB(2);
  issue_xwb(0);
  VM(0);
  conv_store(0);
  issue_xwb(1);
  LGKM0;
  SB;

#pragma unroll 1
  for (int s = 0; s < 29; ++s) body(s, 0);
  body(29, 1);
  body(30, 2);
  body(31, 3);

  // --- epilogue: per-wave LDS transpose, then coalesced float4 stores ---
  SB;   // all waves' slice-31 LDS reads drained before their final SB
  float* ep = (float*)smem + (size_t)wv * (16 * EP_ROWP);  // wave-private 4352B

  float bvj[4];
#pragma unroll
  for (int j = 0; j < 4; ++j) bvj[j] = bias[n0 + wn2 * 64 + j * 16 + lrow];

#pragma unroll
  for (int i = 0; i < 4; ++i) {
#pragma unroll
    for (int j = 0; j < 4; ++j)
#pragma unroll
      for (int r = 0; r < 4; ++r)
        ep[(q * 4 + r) * EP_ROWP + j * 16 + lrow] = acc[i][j][r] + bvj[j];
    // wave-private region: in-wave DS program order suffices, no barrier
#pragma unroll
    for (int it2 = 0; it2 < 4; ++it2) {
      int flat = it2 * 64 + lane;
      int row  = flat >> 4;
      int c16  = flat & 15;
      float4 v = *(const float4*)(ep + row * EP_ROWP + c16 * 4);
      int gm = m0 + wm4 * 64 + i * 16 + row;
      int gn = n0 + wn2 * 64 + c16 * 4;
      *(float4*)(C + (size_t)gm * D_DIM + gn) = v;
    }
  }
}

// ---------------------------------------------------------------------------
// Fallback (only if workspace is too small): correct but slow fp32 path.
// ---------------------------------------------------------------------------
__global__ __launch_bounds__(256) void fallback_kernel(
    const float* __restrict__ x, const float* __restrict__ w_dw,
    const float* __restrict__ b_dw, const float* __restrict__ w_pw,
    const float* __restrict__ b_pw, float* __restrict__ out) {
  __shared__ float ys[D_DIM];
  const int m = blockIdx.x;
  const int l = m & (L_SEQ - 1);
  const int t = threadIdx.x;
  const float* xr = x + (size_t)m * D_DIM;
#pragma unroll
  for (int c = 0; c < 4; ++c) {
    int d = t + c * 256;
    float a = fmaf(xr[d], w_dw[d * 3 + 2], b_dw[d]);
    if (l >= 1) a = fmaf(xr[d - D_DIM], w_dw[d * 3 + 1], a);
    if (l >= 2) a = fmaf(xr[d - 2 * D_DIM], w_dw[d * 3 + 0], a);
    ys[d] = a;
  }
  __syncthreads();
#pragma unroll
  for (int c = 0; c < 4; ++c) {
    int e = t + c * 256;
    const float* wr = w_pw + (size_t)e * D_DIM;
    float a = b_pw[e];
    for (int d = 0; d < D_DIM; ++d) a = fmaf(ys[d], wr[d], a);
    out[(size_t)m * D_DIM + e] = a;
  }
}

extern "C" void kernel_launch(void* const* d_in, const int* in_sizes, int n_in,
                              void* d_out, int out_size, void* d_ws, size_t ws_size,
                              hipStream_t stream) {
  (void)in_sizes; (void)n_in; (void)out_size;
  const float* x    = (const float*)d_in[0];
  const float* w_dw = (const float*)d_in[1];
  const float* b_dw = (const float*)d_in[2];
  const float* w_pw = (const float*)d_in[3];
  const float* b_pw = (const float*)d_in[4];
  float* out = (float*)d_out;

  const size_t w_elems = (size_t)D_DIM * D_DIM;          // 1M bf16 = 2 MB
  const size_t need = w_elems * sizeof(bf16);

  if (ws_size >= need) {
    bf16* wpwb = (bf16*)d_ws;
    cvt_kernel<<<(D_DIM * D_DIM / 8) / 256, 256, 0, stream>>>(w_pw, wpwb);
    dim3 grid(M_TOT / 256, D_DIM / 128);                 // (64, 8): m fastest
    fused_gemm<<<grid, 512, 0, stream>>>(x, w_dw, b_dw, wpwb, b_pw, out);
  } else {
    fallback_kernel<<<M_TOT, 256, 0, stream>>>(x, w_dw, b_dw, w_pw, b_pw, out);
  }
}